// Round 1
// 332.728 us; speedup vs baseline: 1.0961x; 1.0961x over previous
//
#include <hip/hip_runtime.h>

#define N    8192
#define DT   768
#define DO   512
#define BM   128
#define BN   128
#define TI   (N / BM)   // 64
#define TJ   (N / BN)   // 64
#define NTILE (TI * (TI + 1) / 2)   // 2080 upper-triangle tiles

typedef __attribute__((ext_vector_type(8))) short   short8;   // 8 bf16 = 4 VGPRs
typedef __attribute__((ext_vector_type(4))) float   floatx4;

struct alignas(8) us4 { unsigned short x[4]; };

// round-to-nearest-even fp32 -> bf16
__device__ inline unsigned short f2bf(float x) {
    union { float f; unsigned int u; } v; v.f = x;
    unsigned int r = v.u + 0x7fffu + ((v.u >> 16) & 1u);
    return (unsigned short)(r >> 16);
}
__device__ inline float bf2f(unsigned short u) {
    union { unsigned int u; float f; } v; v.u = ((unsigned int)u) << 16;
    return v.f;
}

// async global->LDS, 16B per lane (global_load_lds_dwordx4)
__device__ inline void gl2lds16(const unsigned short* g, unsigned short* l) {
    __builtin_amdgcn_global_load_lds(
        (const __attribute__((address_space(1))) unsigned int*)(const void*)g,
        (__attribute__((address_space(3))) unsigned int*)(void*)l,
        16, 0, 0);
}

// stage one 128x32 A-tile and B-tile (bf16) into LDS via global_load_lds.
// LDS destination stays LINEAR (global_load_lds requires base+lane*16);
// bank-conflict swizzle is applied by permuting the GLOBAL source column:
// LDS chunk (r, s) holds global col-chunk (s ^ ((r>>1)&3)). The matching
// XOR is applied on the ds_read side. This spreads the 16 lanes of a
// fragment read across all 8 16B-slots of the 128B bank period (2-way, free)
// instead of 2 slots (8-way conflict).
template <int D>
__device__ inline void stage_tile(const unsigned short* __restrict__ Xi,
                                  const unsigned short* __restrict__ Xj,
                                  unsigned short* sA, unsigned short* sB,
                                  int i0, int j0, int k, int t) {
    #pragma unroll
    for (int h = 0; h < 2; ++h) {
        const int idx = t + h * 256;        // 0..511; lane-contiguous per wave
        const int r   = idx >> 2;
        const int cs  = ((idx & 3) ^ ((r >> 1) & 3)) << 3;   // swizzled col-chunk
        gl2lds16(Xi + (size_t)(i0 + r) * D + k + cs, &sA[idx * 8]);
        gl2lds16(Xj + (size_t)(j0 + r) * D + k + cs, &sB[idx * 8]);
    }
}

// ---------------- row-normalize fp32 -> bf16 (one wave per row) ----------------
// Single launch covers both matrices: blocks [0, N/4) -> targets (D=768),
// blocks [N/4, 2N/4) -> model_output (D=512). Also zeroes the output scalar.
__global__ void norm_kernel(const float* __restrict__ Tg,
                            const float* __restrict__ Mo,
                            unsigned short* __restrict__ Xt,
                            unsigned short* __restrict__ Xo,
                            float* __restrict__ zero_me) {
    if (blockIdx.x == 0 && threadIdx.x == 0) zero_me[0] = 0.0f;
    int bid = blockIdx.x;
    const float* X; unsigned short* Xn; int D;
    if (bid < N / 4) { X = Tg; Xn = Xt; D = DT; }
    else             { bid -= N / 4; X = Mo; Xn = Xo; D = DO; }
    const int row  = bid * 4 + (threadIdx.x >> 6);
    const int lane = threadIdx.x & 63;
    const float* xr = X + (size_t)row * D;
    float ss = 0.0f;
    for (int c = lane * 4; c < D; c += 256) {
        const floatx4 v = *(const floatx4*)(xr + c);
        ss += v[0] * v[0] + v[1] * v[1] + v[2] * v[2] + v[3] * v[3];
    }
    #pragma unroll
    for (int m = 32; m >= 1; m >>= 1) ss += __shfl_xor(ss, m);
    const float scale = 1.0f / fmaxf(sqrtf(ss), 1e-8f);
    unsigned short* outr = Xn + (size_t)row * D;
    for (int c = lane * 4; c < D; c += 256) {
        const floatx4 v = *(const floatx4*)(xr + c);
        us4 o;
        #pragma unroll
        for (int j = 0; j < 4; ++j) o.x[j] = f2bf(v[j] * scale);
        *(us4*)(outr + c) = o;
    }
}

// ---------------- fused dual-GEMM + softmax-stat tile kernel ----------------
// SYMMETRY: sim matrices are symmetric (a_ij == a_ji, b_ij == b_ji, and the
// teacher weight W = e3(a) is symmetric too). Only tiles with ti <= tj are
// computed (2080 of 4096). Each off-diagonal tile contributes:
//   - row-sums (reduce over lr lanes)  -> rows in ti-range, slot tj*2+wn
//   - col-sums (reduce over lg groups) -> rows in tj-range, slot ti*2+wm
// Diagonal tiles contribute row-sums only (slot ti*2+wn).
// Per row, slots 0..127 are each written exactly once:
//   slot 2b+h for row in tile a:  b>a row-sums | b==a diag | b<a col-sums.
// partials layout: [2*TJ][N][5] floats (Zt, V, UA, Zo, WB) per (slot,row).
__launch_bounds__(256, 3)
__global__ void fused_kernel(const unsigned short* __restrict__ Xt,
                             const unsigned short* __restrict__ Xo,
                             float* __restrict__ partials) {
    __shared__ unsigned short sA[BM * 32];     // 8 KB
    __shared__ unsigned short sB[BN * 32];     // 8 KB
    __shared__ unsigned short sW[64 * 256];    // 32 KB: [idx 0..63][thread 0..255]

    const int t    = threadIdx.x;
    const int lane = t & 63;
    const int w    = t >> 6;
    const int wm   = w >> 1, wn = w & 1;
    const int lr   = lane & 15, lg = lane >> 4;
    const int swz  = (lr >> 1) & 3;            // loop-invariant read swizzle term

    // upper-triangle mapping: bid -> (ti, tj), ti <= tj (uniform scalar loop)
    int rem = blockIdx.x, ti = 0;
    while (rem >= TI - ti) { rem -= TI - ti; ++ti; }
    const int tj = ti + rem;
    const bool offdiag = (ti != tj);
    const int i0 = ti * BM, j0 = tj * BN;

    floatx4 acc[4][4];
    #pragma unroll
    for (int a = 0; a < 4; ++a)
        #pragma unroll
        for (int b = 0; b < 4; ++b)
            acc[a][b] = (floatx4){0.0f, 0.0f, 0.0f, 0.0f};

    // ---- teacher GEMM: S_t tile, K = DT ----
    for (int k = 0; k < DT; k += 32) {
        stage_tile<DT>(Xt, Xt, sA, sB, i0, j0, k, t);
        asm volatile("s_waitcnt vmcnt(0)" ::: "memory");
        __syncthreads();
        short8 af[4], bf[4];
        #pragma unroll
        for (int mi = 0; mi < 4; ++mi)
            af[mi] = *(const short8*)&sA[(wm * 64 + mi * 16 + lr) * 32 + ((lg ^ swz) << 3)];
        #pragma unroll
        for (int ni = 0; ni < 4; ++ni)
            bf[ni] = *(const short8*)&sB[(wn * 64 + ni * 16 + lr) * 32 + ((lg ^ swz) << 3)];
        #pragma unroll
        for (int mi = 0; mi < 4; ++mi)
            #pragma unroll
            for (int ni = 0; ni < 4; ++ni)
                acc[mi][ni] = __builtin_amdgcn_mfma_f32_16x16x32_bf16(
                    af[mi], bf[ni], acc[mi][ni], 0, 0, 0);
        __syncthreads();
    }

    // ---- teacher epilogue: Zt, V, Sum(e3*a) per row (both orientations);
    //      park W=e3 (bf16) in LDS for the student pass ----
    // C/D layout: col = lane&15, row = (lane>>4)*4 + reg
    {
        float czt[4], cvv[4], cua[4];
        #pragma unroll
        for (int ni = 0; ni < 4; ++ni) { czt[ni] = 0.0f; cvv[ni] = 0.0f; cua[ni] = 0.0f; }
        #pragma unroll
        for (int mi = 0; mi < 4; ++mi) {
            #pragma unroll
            for (int r = 0; r < 4; ++r) {
                const int row = wm * 64 + mi * 16 + lg * 4 + r;
                const int gi  = i0 + row;
                float zt = 0.0f, vv = 0.0f, ua = 0.0f;
                #pragma unroll
                for (int ni = 0; ni < 4; ++ni) {
                    const int gj = j0 + wn * 64 + ni * 16 + lr;
                    const float a = acc[mi][ni][r];
                    float ea = __expf(a - 1.0f);
                    if (gi == gj) ea = 0.0f;               // diagonal -> prob 0
                    const float e3 = ea * ea * ea;
                    zt += ea; vv += e3; ua += e3 * a;
                    czt[ni] += ea; cvv[ni] += e3; cua[ni] += e3 * a;
                    sW[(mi * 16 + ni * 4 + r) * 256 + t] = f2bf(e3);
                }
                #pragma unroll
                for (int m = 8; m >= 1; m >>= 1) {
                    zt += __shfl_xor(zt, m);
                    vv += __shfl_xor(vv, m);
                    ua += __shfl_xor(ua, m);
                }
                if (lr == 0) {
                    float* p = partials + ((size_t)(tj * 2 + wn) * N + gi) * 5;
                    p[0] = zt; p[1] = vv; p[2] = ua;
                }
            }
        }
        if (offdiag) {
            #pragma unroll
            for (int ni = 0; ni < 4; ++ni) {
                #pragma unroll
                for (int m = 16; m <= 32; m <<= 1) {
                    czt[ni] += __shfl_xor(czt[ni], m);
                    cvv[ni] += __shfl_xor(cvv[ni], m);
                    cua[ni] += __shfl_xor(cua[ni], m);
                }
            }
            if (lg == 0) {
                #pragma unroll
                for (int ni = 0; ni < 4; ++ni) {
                    const int gj = j0 + wn * 64 + ni * 16 + lr;
                    float* p = partials + ((size_t)(ti * 2 + wm) * N + gj) * 5;
                    p[0] = czt[ni]; p[1] = cvv[ni]; p[2] = cua[ni];
                }
            }
        }
    }
    // No barrier needed: sW is per-thread private; sA/sB free to restage
    // (all reads of the last teacher tile completed before the final barrier).

    // ---- student GEMM: S_o tile, K = DO (same accumulator registers) ----
    #pragma unroll
    for (int a = 0; a < 4; ++a)
        #pragma unroll
        for (int b = 0; b < 4; ++b)
            acc[a][b] = (floatx4){0.0f, 0.0f, 0.0f, 0.0f};

    for (int k = 0; k < DO; k += 32) {
        stage_tile<DO>(Xo, Xo, sA, sB, i0, j0, k, t);
        asm volatile("s_waitcnt vmcnt(0)" ::: "memory");
        __syncthreads();
        short8 af[4], bf[4];
        #pragma unroll
        for (int mi = 0; mi < 4; ++mi)
            af[mi] = *(const short8*)&sA[(wm * 64 + mi * 16 + lr) * 32 + ((lg ^ swz) << 3)];
        #pragma unroll
        for (int ni = 0; ni < 4; ++ni)
            bf[ni] = *(const short8*)&sB[(wn * 64 + ni * 16 + lr) * 32 + ((lg ^ swz) << 3)];
        #pragma unroll
        for (int mi = 0; mi < 4; ++mi)
            #pragma unroll
            for (int ni = 0; ni < 4; ++ni)
                acc[mi][ni] = __builtin_amdgcn_mfma_f32_16x16x32_bf16(
                    af[mi], bf[ni], acc[mi][ni], 0, 0, 0);
        __syncthreads();
    }

    // ---- final epilogue: Zo, Sum(W*b) per row (both orientations) ----
    {
        float czo[4], cwb[4];
        #pragma unroll
        for (int ni = 0; ni < 4; ++ni) { czo[ni] = 0.0f; cwb[ni] = 0.0f; }
        #pragma unroll
        for (int mi = 0; mi < 4; ++mi) {
            #pragma unroll
            for (int r = 0; r < 4; ++r) {
                const int row = wm * 64 + mi * 16 + lg * 4 + r;
                const int gi  = i0 + row;
                float zo = 0.0f, wb = 0.0f;
                #pragma unroll
                for (int ni = 0; ni < 4; ++ni) {
                    const int gj = j0 + wn * 64 + ni * 16 + lr;
                    const float b = acc[mi][ni][r];
                    float eb = __expf(b - 1.0f);
                    if (gi == gj) eb = 0.0f;
                    const float wgt = bf2f(sW[(mi * 16 + ni * 4 + r) * 256 + t]);
                    zo += eb; wb += wgt * b;   // diag: W==0 -> no contribution
                    czo[ni] += eb; cwb[ni] += wgt * b;
                }
                #pragma unroll
                for (int m = 8; m >= 1; m >>= 1) {
                    zo += __shfl_xor(zo, m);
                    wb += __shfl_xor(wb, m);
                }
                if (lr == 0) {
                    float* p = partials + ((size_t)(tj * 2 + wn) * N + gi) * 5;
                    p[3] = zo; p[4] = wb;
                }
            }
        }
        if (offdiag) {
            #pragma unroll
            for (int ni = 0; ni < 4; ++ni) {
                #pragma unroll
                for (int m = 16; m <= 32; m <<= 1) {
                    czo[ni] += __shfl_xor(czo[ni], m);
                    cwb[ni] += __shfl_xor(cwb[ni], m);
                }
            }
            if (lg == 0) {
                #pragma unroll
                for (int ni = 0; ni < 4; ++ni) {
                    const int gj = j0 + wn * 64 + ni * 16 + lr;
                    float* p = partials + ((size_t)(ti * 2 + wm) * N + gj) * 5;
                    p[3] = czo[ni]; p[4] = cwb[ni];
                }
            }
        }
    }
}

// ---------------- final per-row combine + scalar reduce ----------------
__global__ void reduce_kernel(const float* __restrict__ partials,
                              float* __restrict__ out) {
    const int i = blockIdx.x * 256 + threadIdx.x;   // row
    float zt = 0.0f, vv = 0.0f, ua = 0.0f, zo = 0.0f, wb = 0.0f;
    for (int jb = 0; jb < 2 * TJ; ++jb) {
        const float* p = partials + ((size_t)jb * N + i) * 5;
        zt += p[0]; vv += p[1]; ua += p[2]; zo += p[3]; wb += p[4];
    }
    // loss_i = (U + V*log(Zo/Zt)) / Zt^3, U = ua - wb
    float li = (ua - wb + vv * __logf(zo / zt)) / (zt * zt * zt);
    #pragma unroll
    for (int m = 32; m >= 1; m >>= 1) li += __shfl_xor(li, m);
    __shared__ float wsh[4];
    const int w = threadIdx.x >> 6;
    if ((threadIdx.x & 63) == 0) wsh[w] = li;
    __syncthreads();
    if (threadIdx.x == 0) {
        const float s = (wsh[0] + wsh[1] + wsh[2] + wsh[3]) *
                        (1.0f / ((float)N * (float)N));   // WEIGHT=1, mean over N^2
        atomicAdd(out, s);
    }
}

extern "C" void kernel_launch(void* const* d_in, const int* in_sizes, int n_in,
                              void* d_out, int out_size, void* d_ws, size_t ws_size,
                              hipStream_t stream) {
    (void)in_sizes; (void)n_in; (void)out_size; (void)ws_size;
    const float* mo = (const float*)d_in[0];   // model_output [8192,512] fp32
    const float* tg = (const float*)d_in[1];   // targets      [8192,768] fp32
    float* out = (float*)d_out;

    char* ws = (char*)d_ws;
    unsigned short* Xt = (unsigned short*)ws;                          // 12.58 MB
    unsigned short* Xo = (unsigned short*)(ws + (size_t)N * DT * 2);   //  8.39 MB
    float* partials    = (float*)(ws + (size_t)N * DT * 2 + (size_t)N * DO * 2);
    // partials: 128 * 8192 * 5 * 4 B = 20.97 MB; total ws use ~41.9 MB

    norm_kernel<<<2 * (N / 4), 256, 0, stream>>>(tg, mo, Xt, Xo, out);  // also zeroes out
    fused_kernel<<<NTILE, 256, 0, stream>>>(Xt, Xo, partials);
    reduce_kernel<<<N / 256, 256, 0, stream>>>(partials, out);
}

// Round 2
// 305.505 us; speedup vs baseline: 1.1937x; 1.0891x over previous
//
#include <hip/hip_runtime.h>

#define N    8192
#define DT   768
#define DO   512
#define BM   128
#define BN   128
#define TI   (N / BM)   // 64
#define TJ   (N / BN)   // 64
#define NTILE (TI * (TI + 1) / 2)   // 2080 upper-triangle tiles (2080 % 8 == 0)
#define NSLOT (2 * TJ)              // 128 partial slots per row
#define PL    ((size_t)NSLOT * N)   // one SoA plane: 128*8192 floats = 4 MB

typedef __attribute__((ext_vector_type(8))) short   short8;   // 8 bf16 = 4 VGPRs
typedef __attribute__((ext_vector_type(4))) float   floatx4;

struct alignas(8) us4 { unsigned short x[4]; };

// round-to-nearest-even fp32 -> bf16
__device__ inline unsigned short f2bf(float x) {
    union { float f; unsigned int u; } v; v.f = x;
    unsigned int r = v.u + 0x7fffu + ((v.u >> 16) & 1u);
    return (unsigned short)(r >> 16);
}
__device__ inline float bf2f(unsigned short u) {
    union { unsigned int u; float f; } v; v.u = ((unsigned int)u) << 16;
    return v.f;
}

// async global->LDS, 16B per lane (global_load_lds_dwordx4)
__device__ inline void gl2lds16(const unsigned short* g, unsigned short* l) {
    __builtin_amdgcn_global_load_lds(
        (const __attribute__((address_space(1))) unsigned int*)(const void*)g,
        (__attribute__((address_space(3))) unsigned int*)(void*)l,
        16, 0, 0);
}

// stage one 128x32 A-tile and B-tile (bf16) into LDS via global_load_lds.
// LDS destination stays LINEAR (global_load_lds requires base+lane*16);
// bank-conflict swizzle is applied by permuting the GLOBAL source column:
// LDS chunk (r, s) holds global col-chunk (s ^ ((r>>1)&3)). The matching
// XOR is applied on the ds_read side (2-way residual conflict = free).
template <int D>
__device__ inline void stage_tile(const unsigned short* __restrict__ Xi,
                                  const unsigned short* __restrict__ Xj,
                                  unsigned short* sA, unsigned short* sB,
                                  int i0, int j0, int k, int t) {
    #pragma unroll
    for (int h = 0; h < 2; ++h) {
        const int idx = t + h * 256;        // 0..511; lane-contiguous per wave
        const int r   = idx >> 2;
        const int cs  = ((idx & 3) ^ ((r >> 1) & 3)) << 3;   // swizzled col-chunk
        gl2lds16(Xi + (size_t)(i0 + r) * D + k + cs, &sA[idx * 8]);
        gl2lds16(Xj + (size_t)(j0 + r) * D + k + cs, &sB[idx * 8]);
    }
}

// ---------------- row-normalize fp32 -> bf16 (one wave per row) ----------------
// Single launch covers both matrices: blocks [0, N/4) -> targets (D=768),
// blocks [N/4, 2N/4) -> model_output (D=512). Also zeroes the output scalar.
__global__ void norm_kernel(const float* __restrict__ Tg,
                            const float* __restrict__ Mo,
                            unsigned short* __restrict__ Xt,
                            unsigned short* __restrict__ Xo,
                            float* __restrict__ zero_me) {
    if (blockIdx.x == 0 && threadIdx.x == 0) zero_me[0] = 0.0f;
    int bid = blockIdx.x;
    const float* X; unsigned short* Xn; int D;
    if (bid < N / 4) { X = Tg; Xn = Xt; D = DT; }
    else             { bid -= N / 4; X = Mo; Xn = Xo; D = DO; }
    const int row  = bid * 4 + (threadIdx.x >> 6);
    const int lane = threadIdx.x & 63;
    const float* xr = X + (size_t)row * D;
    float ss = 0.0f;
    for (int c = lane * 4; c < D; c += 256) {
        const floatx4 v = *(const floatx4*)(xr + c);
        ss += v[0] * v[0] + v[1] * v[1] + v[2] * v[2] + v[3] * v[3];
    }
    #pragma unroll
    for (int m = 32; m >= 1; m >>= 1) ss += __shfl_xor(ss, m);
    const float scale = 1.0f / fmaxf(sqrtf(ss), 1e-8f);
    unsigned short* outr = Xn + (size_t)row * D;
    for (int c = lane * 4; c < D; c += 256) {
        const floatx4 v = *(const floatx4*)(xr + c);
        us4 o;
        #pragma unroll
        for (int j = 0; j < 4; ++j) o.x[j] = f2bf(v[j] * scale);
        *(us4*)(outr + c) = o;
    }
}

// ---------------- fused dual-GEMM + softmax-stat tile kernel ----------------
// SYMMETRY: sim matrices are symmetric, and teacher weight W = e3(a) is too.
// Only tiles with ti <= tj are computed (2080 of 4096). Each off-diagonal tile:
//   - row-sums (reduce over lr lanes)  -> rows in ti-range, slot tj*2+wn
//   - col-sums (reduce over lg groups) -> rows in tj-range, slot ti*2+wm
// Diagonal tiles contribute row-sums only. Per row, slots 0..127 each written
// exactly once.
// partials layout (SoA for full-line stores): 5 planes [NSLOT][N] f32
//   plane 0..4 = Zt, V, UA, Zo, WB.  Col-sum stores: 16 lanes x 4B contiguous
//   = one full 64B line per instruction (kills the R1 RMW write amplification).
__launch_bounds__(256, 3)
__global__ void fused_kernel(const unsigned short* __restrict__ Xt,
                             const unsigned short* __restrict__ Xo,
                             float* __restrict__ partials) {
    __shared__ unsigned short sA[BM * 32];     // 8 KB
    __shared__ unsigned short sB[BN * 32];     // 8 KB
    __shared__ unsigned short sW[64 * 256];    // 32 KB: [idx 0..63][thread 0..255]

    const int t    = threadIdx.x;
    const int lane = t & 63;
    const int w    = t >> 6;
    const int wm   = w >> 1, wn = w & 1;
    const int lr   = lane & 15, lg = lane >> 4;
    const int swz  = (lr >> 1) & 3;            // loop-invariant read swizzle term

    // Bijective chunked XCD swizzle (m204; NTILE % 8 == 0 -> exact):
    // XCD k owns triangle-enumeration range [k*260, (k+1)*260) -> long runs of
    // constant ti (A-panel L2-resident per XCD), tj walking sequentially.
    const int swb = (blockIdx.x & 7) * (NTILE / 8) + (blockIdx.x >> 3);
    // upper-triangle mapping: swb -> (ti, tj), ti <= tj (uniform scalar loop)
    int rem = swb, ti = 0;
    while (rem >= TI - ti) { rem -= TI - ti; ++ti; }
    const int tj = ti + rem;
    const bool offdiag = (ti != tj);
    const int i0 = ti * BM, j0 = tj * BN;

    floatx4 acc[4][4];
    #pragma unroll
    for (int a = 0; a < 4; ++a)
        #pragma unroll
        for (int b = 0; b < 4; ++b)
            acc[a][b] = (floatx4){0.0f, 0.0f, 0.0f, 0.0f};

    // ---- teacher GEMM: S_t tile, K = DT ----
    for (int k = 0; k < DT; k += 32) {
        stage_tile<DT>(Xt, Xt, sA, sB, i0, j0, k, t);
        asm volatile("s_waitcnt vmcnt(0)" ::: "memory");
        __syncthreads();
        short8 af[4], bf[4];
        #pragma unroll
        for (int mi = 0; mi < 4; ++mi)
            af[mi] = *(const short8*)&sA[(wm * 64 + mi * 16 + lr) * 32 + ((lg ^ swz) << 3)];
        #pragma unroll
        for (int ni = 0; ni < 4; ++ni)
            bf[ni] = *(const short8*)&sB[(wn * 64 + ni * 16 + lr) * 32 + ((lg ^ swz) << 3)];
        #pragma unroll
        for (int mi = 0; mi < 4; ++mi)
            #pragma unroll
            for (int ni = 0; ni < 4; ++ni)
                acc[mi][ni] = __builtin_amdgcn_mfma_f32_16x16x32_bf16(
                    af[mi], bf[ni], acc[mi][ni], 0, 0, 0);
        __syncthreads();
    }

    // ---- teacher epilogue: Zt, V, Sum(e3*a) per row (both orientations);
    //      park W=e3 (bf16) in LDS for the student pass ----
    // C/D layout: col = lane&15, row = (lane>>4)*4 + reg
    {
        float czt[4], cvv[4], cua[4];
        #pragma unroll
        for (int ni = 0; ni < 4; ++ni) { czt[ni] = 0.0f; cvv[ni] = 0.0f; cua[ni] = 0.0f; }
        #pragma unroll
        for (int mi = 0; mi < 4; ++mi) {
            #pragma unroll
            for (int r = 0; r < 4; ++r) {
                const int row = wm * 64 + mi * 16 + lg * 4 + r;
                const int gi  = i0 + row;
                float zt = 0.0f, vv = 0.0f, ua = 0.0f;
                #pragma unroll
                for (int ni = 0; ni < 4; ++ni) {
                    const int gj = j0 + wn * 64 + ni * 16 + lr;
                    const float a = acc[mi][ni][r];
                    float ea = __expf(a - 1.0f);
                    if (gi == gj) ea = 0.0f;               // diagonal -> prob 0
                    const float e3 = ea * ea * ea;
                    zt += ea; vv += e3; ua += e3 * a;
                    czt[ni] += ea; cvv[ni] += e3; cua[ni] += e3 * a;
                    sW[(mi * 16 + ni * 4 + r) * 256 + t] = f2bf(e3);
                }
                #pragma unroll
                for (int m = 8; m >= 1; m >>= 1) {
                    zt += __shfl_xor(zt, m);
                    vv += __shfl_xor(vv, m);
                    ua += __shfl_xor(ua, m);
                }
                if (lr == 0) {
                    const size_t base = (size_t)(tj * 2 + wn) * N + gi;
                    partials[0 * PL + base] = zt;
                    partials[1 * PL + base] = vv;
                    partials[2 * PL + base] = ua;
                }
            }
        }
        if (offdiag) {
            #pragma unroll
            for (int ni = 0; ni < 4; ++ni) {
                #pragma unroll
                for (int m = 16; m <= 32; m <<= 1) {
                    czt[ni] += __shfl_xor(czt[ni], m);
                    cvv[ni] += __shfl_xor(cvv[ni], m);
                    cua[ni] += __shfl_xor(cua[ni], m);
                }
            }
            if (lg == 0) {
                #pragma unroll
                for (int ni = 0; ni < 4; ++ni) {
                    const int gj = j0 + wn * 64 + ni * 16 + lr;   // lr 0..15: contiguous
                    const size_t base = (size_t)(ti * 2 + wm) * N + gj;
                    partials[0 * PL + base] = czt[ni];
                    partials[1 * PL + base] = cvv[ni];
                    partials[2 * PL + base] = cua[ni];
                }
            }
        }
    }
    // No barrier needed: sW is per-thread private; sA/sB free to restage
    // (all reads of the last teacher tile completed before the final barrier).

    // ---- student GEMM: S_o tile, K = DO (same accumulator registers) ----
    #pragma unroll
    for (int a = 0; a < 4; ++a)
        #pragma unroll
        for (int b = 0; b < 4; ++b)
            acc[a][b] = (floatx4){0.0f, 0.0f, 0.0f, 0.0f};

    for (int k = 0; k < DO; k += 32) {
        stage_tile<DO>(Xo, Xo, sA, sB, i0, j0, k, t);
        asm volatile("s_waitcnt vmcnt(0)" ::: "memory");
        __syncthreads();
        short8 af[4], bf[4];
        #pragma unroll
        for (int mi = 0; mi < 4; ++mi)
            af[mi] = *(const short8*)&sA[(wm * 64 + mi * 16 + lr) * 32 + ((lg ^ swz) << 3)];
        #pragma unroll
        for (int ni = 0; ni < 4; ++ni)
            bf[ni] = *(const short8*)&sB[(wn * 64 + ni * 16 + lr) * 32 + ((lg ^ swz) << 3)];
        #pragma unroll
        for (int mi = 0; mi < 4; ++mi)
            #pragma unroll
            for (int ni = 0; ni < 4; ++ni)
                acc[mi][ni] = __builtin_amdgcn_mfma_f32_16x16x32_bf16(
                    af[mi], bf[ni], acc[mi][ni], 0, 0, 0);
        __syncthreads();
    }

    // ---- final epilogue: Zo, Sum(W*b) per row (both orientations) ----
    {
        float czo[4], cwb[4];
        #pragma unroll
        for (int ni = 0; ni < 4; ++ni) { czo[ni] = 0.0f; cwb[ni] = 0.0f; }
        #pragma unroll
        for (int mi = 0; mi < 4; ++mi) {
            #pragma unroll
            for (int r = 0; r < 4; ++r) {
                const int row = wm * 64 + mi * 16 + lg * 4 + r;
                const int gi  = i0 + row;
                float zo = 0.0f, wb = 0.0f;
                #pragma unroll
                for (int ni = 0; ni < 4; ++ni) {
                    const int gj = j0 + wn * 64 + ni * 16 + lr;
                    const float b = acc[mi][ni][r];
                    float eb = __expf(b - 1.0f);
                    if (gi == gj) eb = 0.0f;
                    const float wgt = bf2f(sW[(mi * 16 + ni * 4 + r) * 256 + t]);
                    zo += eb; wb += wgt * b;   // diag: W==0 -> no contribution
                    czo[ni] += eb; cwb[ni] += wgt * b;
                }
                #pragma unroll
                for (int m = 8; m >= 1; m >>= 1) {
                    zo += __shfl_xor(zo, m);
                    wb += __shfl_xor(wb, m);
                }
                if (lr == 0) {
                    const size_t base = (size_t)(tj * 2 + wn) * N + gi;
                    partials[3 * PL + base] = zo;
                    partials[4 * PL + base] = wb;
                }
            }
        }
        if (offdiag) {
            #pragma unroll
            for (int ni = 0; ni < 4; ++ni) {
                #pragma unroll
                for (int m = 16; m <= 32; m <<= 1) {
                    czo[ni] += __shfl_xor(czo[ni], m);
                    cwb[ni] += __shfl_xor(cwb[ni], m);
                }
            }
            if (lg == 0) {
                #pragma unroll
                for (int ni = 0; ni < 4; ++ni) {
                    const int gj = j0 + wn * 64 + ni * 16 + lr;   // lr 0..15: contiguous
                    const size_t base = (size_t)(ti * 2 + wm) * N + gj;
                    partials[3 * PL + base] = czo[ni];
                    partials[4 * PL + base] = cwb[ni];
                }
            }
        }
    }
}

// ---------------- final per-row combine + scalar reduce ----------------
__global__ void reduce_kernel(const float* __restrict__ partials,
                              float* __restrict__ out) {
    const int i = blockIdx.x * 256 + threadIdx.x;   // row
    float zt = 0.0f, vv = 0.0f, ua = 0.0f, zo = 0.0f, wb = 0.0f;
    for (int jb = 0; jb < NSLOT; ++jb) {
        const size_t base = (size_t)jb * N + i;     // stride-1 across threads
        zt += partials[0 * PL + base];
        vv += partials[1 * PL + base];
        ua += partials[2 * PL + base];
        zo += partials[3 * PL + base];
        wb += partials[4 * PL + base];
    }
    // loss_i = (U + V*log(Zo/Zt)) / Zt^3, U = ua - wb
    float li = (ua - wb + vv * __logf(zo / zt)) / (zt * zt * zt);
    #pragma unroll
    for (int m = 32; m >= 1; m >>= 1) li += __shfl_xor(li, m);
    __shared__ float wsh[4];
    const int w = threadIdx.x >> 6;
    if ((threadIdx.x & 63) == 0) wsh[w] = li;
    __syncthreads();
    if (threadIdx.x == 0) {
        const float s = (wsh[0] + wsh[1] + wsh[2] + wsh[3]) *
                        (1.0f / ((float)N * (float)N));   // WEIGHT=1, mean over N^2
        atomicAdd(out, s);
    }
}

extern "C" void kernel_launch(void* const* d_in, const int* in_sizes, int n_in,
                              void* d_out, int out_size, void* d_ws, size_t ws_size,
                              hipStream_t stream) {
    (void)in_sizes; (void)n_in; (void)out_size; (void)ws_size;
    const float* mo = (const float*)d_in[0];   // model_output [8192,512] fp32
    const float* tg = (const float*)d_in[1];   // targets      [8192,768] fp32
    float* out = (float*)d_out;

    char* ws = (char*)d_ws;
    unsigned short* Xt = (unsigned short*)ws;                          // 12.58 MB
    unsigned short* Xo = (unsigned short*)(ws + (size_t)N * DT * 2);   //  8.39 MB
    float* partials    = (float*)(ws + (size_t)N * DT * 2 + (size_t)N * DO * 2);
    // partials: 5 planes * 128 * 8192 * 4 B = 20.97 MB; total ws use ~41.9 MB

    norm_kernel<<<2 * (N / 4), 256, 0, stream>>>(tg, mo, Xt, Xo, out);  // also zeroes out
    fused_kernel<<<NTILE, 256, 0, stream>>>(Xt, Xo, partials);
    reduce_kernel<<<N / 256, 256, 0, stream>>>(partials, out);
}